// Round 17
// baseline (185.076 us; speedup 1.0000x reference)
//
#include <hip/hip_runtime.h>
#include <math.h>

#define DD    512
#define NN    32768      // B*L nodes
#define EE    262144     // edges (without self loops)

typedef float f32x4 __attribute__((ext_vector_type(4)));
typedef __bf16 bf16x8 __attribute__((ext_vector_type(8)));

#define AS1 __attribute__((address_space(1)))
#define AS3 __attribute__((address_space(3)))

// ---------------- CSR build ----------------
__global__ void k_zero(int* __restrict__ cnt) {
    int i = blockIdx.x * 256 + threadIdx.x;
    if (i < NN) cnt[i] = 0;
}

__global__ void k_count(const int* __restrict__ dst, int* __restrict__ cnt) {
    int e = blockIdx.x * 256 + threadIdx.x;
    if (e < EE) atomicAdd(&cnt[dst[e]], 1);
}

__global__ __launch_bounds__(1024) void k_scan(
    const int* __restrict__ cnt, int* __restrict__ offs,
    int* __restrict__ cursor, float* __restrict__ dinv)
{
    __shared__ int part[1024];
    int t = threadIdx.x;
    int base = t * 32;
    int local[32];
    int s = 0;
#pragma unroll
    for (int i = 0; i < 32; ++i) { local[i] = s; s += cnt[base + i]; }
    part[t] = s;
    __syncthreads();
    for (int off = 1; off < 1024; off <<= 1) {
        int v = (t >= off) ? part[t - off] : 0;
        __syncthreads();
        part[t] += v;
        __syncthreads();
    }
    int prev = (t == 0) ? 0 : part[t - 1];
#pragma unroll
    for (int i = 0; i < 32; ++i) {
        int o = prev + local[i];
        offs[base + i] = o;
        cursor[base + i] = o;
        dinv[base + i] = rsqrtf((float)cnt[base + i] + 1.0f);
    }
    if (t == 1023) offs[NN] = part[1023];
}

__global__ void k_fill(const int* __restrict__ src, const int* __restrict__ dst,
                       int* __restrict__ cursor, int* __restrict__ csr) {
    int e = blockIdx.x * 256 + threadIdx.x;
    if (e < EE) {
        int d = dst[e];
        int p = atomicAdd(&cursor[d], 1);
        csr[p] = src[e];
    }
}

// ---------------- weight transpose + convert: Wt[n][k] = (bf16)W[k][n] ----------------
__global__ __launch_bounds__(256) void k_wt(const float* __restrict__ W1, const float* __restrict__ Wg,
                                            __bf16* __restrict__ W1t, __bf16* __restrict__ Wgt) {
    __shared__ float tile[32][33];
    const float* W = blockIdx.z ? Wg : W1;
    __bf16* Wt = blockIdx.z ? Wgt : W1t;
    int x0 = blockIdx.x * 32;   // n block
    int y0 = blockIdx.y * 32;   // k block
    int tx = threadIdx.x;       // 0..31
    for (int j = threadIdx.y; j < 32; j += 8)
        tile[j][tx] = W[(size_t)(y0 + j) * DD + x0 + tx];
    __syncthreads();
    for (int j = threadIdx.y; j < 32; j += 8)
        Wt[(size_t)(x0 + j) * DD + y0 + tx] = (__bf16)tile[tx][j];
}

// ---------------- GEMM1: weight-stationary, LDS slab (r13 structure, measured best) ----------------
// Block: 8 waves x 32 cols = 256-col n-slice; 256 rows via 8 m-tiles of 32. Grid 256.
// W slice per wave in regs (wf[2][16] = 128 VGPR). A fp32 reg-staged + cvt into
// kf-subtiled conflict-free slab (chunk d = kf*128 + r*4 + s; source k-chunk
// kf*4 + (s^((r>>1)&3))). One __syncthreads per m-tile (drain hidden: staging
// issued a full m-tile of compute earlier).
__global__ __launch_bounds__(512, 2) void k_gemm1(
    const float* __restrict__ A,
    const __bf16* __restrict__ Wt,
    __bf16* __restrict__ Cout,
    const float* __restrict__ bias,
    const float* __restrict__ gamma, const float* __restrict__ beta,
    const float* __restrict__ mean, const float* __restrict__ var,
    const float* __restrict__ alphap)
{
    __shared__ __bf16 slab[2][16384];   // 2 x 32KB

    const int t    = threadIdx.x;
    const int lane = t & 63;
    const int wv   = t >> 6;
    const int l15  = lane & 15;
    const int lhi  = lane >> 4;
    const int work = ((blockIdx.x & 7) << 5) + (blockIdx.x >> 3);  // bijective 256; XCD-affine
    const int nsl  = work & 1;
    const int mb   = work >> 1;
    const int mbase   = mb * 256;
    const int colbase = nsl * 256 + wv * 32;

    bf16x8 wf[2][16];
#pragma unroll
    for (int C = 0; C < 2; ++C)
#pragma unroll
        for (int kf = 0; kf < 16; ++kf) {
            int col = colbase + C * 16 + l15;
            wf[C][kf] = *(const bf16x8*)(Wt + (size_t)col * DD + kf * 32 + lhi * 8);
        }

    float s0, s1, t0, t1, al;
    {
        int c0 = colbase + l15, c1 = c0 + 16;
        float r0 = rsqrtf(var[c0] + 1e-5f), r1 = rsqrtf(var[c1] + 1e-5f);
        s0 = gamma[c0] * r0;  s1 = gamma[c1] * r1;
        t0 = (bias[c0] - mean[c0]) * s0 + beta[c0];
        t1 = (bias[c1] - mean[c1]) * s1 + beta[c1];
        al = alphap[0];
    }

    float4 fa[4][2];

    auto loadA1 = [&](int mt) {
#pragma unroll
        for (int q = 0; q < 4; ++q) {
            int d = q * 512 + t;
            int kf = d >> 7, r = (d >> 2) & 31, s = d & 3;
            int c = kf * 4 + (s ^ ((r >> 1) & 3));
            const float* g = A + (size_t)(mbase + mt * 32 + r) * DD + c * 8;
            fa[q][0] = *(const float4*)g;
            fa[q][1] = *(const float4*)(g + 4);
        }
    };
    auto writeA1 = [&](int bb) {
#pragma unroll
        for (int q = 0; q < 4; ++q) {
            int d = q * 512 + t;
            bf16x8 o;
            o[0] = (__bf16)fa[q][0].x; o[1] = (__bf16)fa[q][0].y;
            o[2] = (__bf16)fa[q][0].z; o[3] = (__bf16)fa[q][0].w;
            o[4] = (__bf16)fa[q][1].x; o[5] = (__bf16)fa[q][1].y;
            o[6] = (__bf16)fa[q][1].z; o[7] = (__bf16)fa[q][1].w;
            *(bf16x8*)&slab[bb][(size_t)d * 8] = o;
        }
    };

    loadA1(0); writeA1(0);
    __syncthreads();

#pragma unroll
    for (int mt = 0; mt < 8; ++mt) {
        const int cur = mt & 1, nxt = cur ^ 1;

        if (mt < 7) loadA1(mt + 1);

        f32x4 acc[2][2] = {};
        const __bf16* sl = &slab[cur][0];
#pragma unroll
        for (int kf = 0; kf < 16; ++kf) {
            int r0 = l15, r1 = 16 + l15;
            int sA = lhi ^ ((r0 >> 1) & 3);
            int sB = lhi ^ ((r1 >> 1) & 3);
            bf16x8 a0 = *(const bf16x8*)&sl[(kf * 128 + r0 * 4 + sA) * 8];
            bf16x8 a1 = *(const bf16x8*)&sl[(kf * 128 + r1 * 4 + sB) * 8];
            acc[0][0] = __builtin_amdgcn_mfma_f32_16x16x32_bf16(a0, wf[0][kf], acc[0][0], 0, 0, 0);
            acc[0][1] = __builtin_amdgcn_mfma_f32_16x16x32_bf16(a0, wf[1][kf], acc[0][1], 0, 0, 0);
            acc[1][0] = __builtin_amdgcn_mfma_f32_16x16x32_bf16(a1, wf[0][kf], acc[1][0], 0, 0, 0);
            acc[1][1] = __builtin_amdgcn_mfma_f32_16x16x32_bf16(a1, wf[1][kf], acc[1][1], 0, 0, 0);
        }

#pragma unroll
        for (int R = 0; R < 2; ++R)
#pragma unroll
            for (int C = 0; C < 2; ++C) {
                int col  = colbase + C * 16 + l15;
                int rowb = mbase + mt * 32 + R * 16 + (lhi << 2);
                float ss = C ? s1 : s0, tt = C ? t1 : t0;
#pragma unroll
                for (int j = 0; j < 4; ++j) {
                    float x = acc[R][C][j] * ss + tt;
                    x = (x >= 0.0f) ? x : al * x;
                    Cout[(size_t)(rowb + j) * DD + col] = (__bf16)x;
                }
            }

        if (mt < 7) writeA1(nxt);
        __syncthreads();
    }
}

// ---------------- GEMM2: barrier-free weight-stationary, A direct global->VGPR ----------------
// No LDS, no barriers. Each wave free-runs: W (32 cols x 512 K) in regs, A-fragments
// loaded straight from global (L1-resident: 32KB slab shared read-only by 8 waves).
// Depth-2 software pipeline in NAMED registers (even/odd slots, no dynamic indexing).
// out = A@Wg bf16 (unscaled; dinv applied in gather).
__global__ __launch_bounds__(512) void k_gemm2_bf(
    const __bf16* __restrict__ A,
    const __bf16* __restrict__ Wt,
    __bf16* __restrict__ Cout)
{
    const int t    = threadIdx.x;
    const int lane = t & 63;
    const int wv   = t >> 6;
    const int l15  = lane & 15;
    const int lhi  = lane >> 4;
    const int work = ((blockIdx.x & 7) << 5) + (blockIdx.x >> 3);  // bijective 256; XCD-affine
    const int nsl  = work & 1;
    const int mb   = work >> 1;
    const int mbase   = mb * 256;
    const int colbase = nsl * 256 + wv * 32;

    bf16x8 wf[2][16];
#pragma unroll
    for (int C = 0; C < 2; ++C)
#pragma unroll
        for (int kf = 0; kf < 16; ++kf) {
            int col = colbase + C * 16 + l15;
            wf[C][kf] = *(const bf16x8*)(Wt + (size_t)col * DD + kf * 32 + lhi * 8);
        }

    // per-lane A base: row = mbase + l15 (+16 for group 1), k-offset lhi*8
    const __bf16* pA0 = A + (size_t)(mbase + l15) * DD + lhi * 8;
    const __bf16* pA1 = pA0 + 16 * DD;

#pragma unroll
    for (int mt = 0; mt < 8; ++mt) {
        const __bf16* q0 = pA0 + (size_t)mt * 32 * DD;
        const __bf16* q1 = pA1 + (size_t)mt * 32 * DD;

        f32x4 acc[2][2] = {};

        // depth-2 pipeline: even/odd named slots
        bf16x8 a0e = *(const bf16x8*)(q0);
        bf16x8 a1e = *(const bf16x8*)(q1);
        bf16x8 a0o = *(const bf16x8*)(q0 + 32);
        bf16x8 a1o = *(const bf16x8*)(q1 + 32);

#pragma unroll
        for (int kf = 0; kf < 16; kf += 2) {
            acc[0][0] = __builtin_amdgcn_mfma_f32_16x16x32_bf16(a0e, wf[0][kf], acc[0][0], 0, 0, 0);
            acc[0][1] = __builtin_amdgcn_mfma_f32_16x16x32_bf16(a0e, wf[1][kf], acc[0][1], 0, 0, 0);
            acc[1][0] = __builtin_amdgcn_mfma_f32_16x16x32_bf16(a1e, wf[0][kf], acc[1][0], 0, 0, 0);
            acc[1][1] = __builtin_amdgcn_mfma_f32_16x16x32_bf16(a1e, wf[1][kf], acc[1][1], 0, 0, 0);
            if (kf + 2 < 16) {
                a0e = *(const bf16x8*)(q0 + (kf + 2) * 32);
                a1e = *(const bf16x8*)(q1 + (kf + 2) * 32);
            }
            acc[0][0] = __builtin_amdgcn_mfma_f32_16x16x32_bf16(a0o, wf[0][kf + 1], acc[0][0], 0, 0, 0);
            acc[0][1] = __builtin_amdgcn_mfma_f32_16x16x32_bf16(a0o, wf[1][kf + 1], acc[0][1], 0, 0, 0);
            acc[1][0] = __builtin_amdgcn_mfma_f32_16x16x32_bf16(a1o, wf[0][kf + 1], acc[1][0], 0, 0, 0);
            acc[1][1] = __builtin_amdgcn_mfma_f32_16x16x32_bf16(a1o, wf[1][kf + 1], acc[1][1], 0, 0, 0);
            if (kf + 3 < 16) {
                a0o = *(const bf16x8*)(q0 + (kf + 3) * 32);
                a1o = *(const bf16x8*)(q1 + (kf + 3) * 32);
            }
        }

#pragma unroll
        for (int R = 0; R < 2; ++R)
#pragma unroll
            for (int C = 0; C < 2; ++C) {
                int col  = colbase + C * 16 + l15;
                int rowb = mbase + mt * 32 + R * 16 + (lhi << 2);
#pragma unroll
                for (int j = 0; j < 4; ++j)
                    Cout[(size_t)(rowb + j) * DD + col] = (__bf16)acc[R][C][j];
            }
    }
}

// ---------------- fused gather (deg-weighted) + bias + PReLU + L2 norm + residual ----------------
__global__ __launch_bounds__(256) void k_gather_final(
    const int* __restrict__ offs, const int* __restrict__ csr,
    const __bf16* __restrict__ xws, const float* __restrict__ dinv,
    const float* __restrict__ bg, const float* __restrict__ alpha2,
    const float* __restrict__ text, float* __restrict__ out)
{
    int blk = blockIdx.x;                              // 0..8191
    int sb  = ((blk & 7) << 10) + (blk >> 3);          // XCD-chunked (bijective)
    int wave = threadIdx.x >> 6;
    int lane = threadIdx.x & 63;
    int node = sb * 4 + wave;
    int c = lane * 8;
    int beg = offs[node], end = offs[node + 1];
    int ne = end - beg;

    float dn = dinv[node];
    bf16x8 sv = *(const bf16x8*)(xws + (size_t)node * DD + c);   // self loop
    float a[8];
#pragma unroll
    for (int i = 0; i < 8; ++i) a[i] = dn * (float)sv[i];

    int k = 0;
    for (; k + 4 <= ne; k += 4) {
        int s0 = csr[beg + k + 0];
        int s1 = csr[beg + k + 1];
        int s2 = csr[beg + k + 2];
        int s3 = csr[beg + k + 3];
        float d0 = dinv[s0], d1 = dinv[s1], d2 = dinv[s2], d3 = dinv[s3];
        bf16x8 v0 = *(const bf16x8*)(xws + (size_t)s0 * DD + c);
        bf16x8 v1 = *(const bf16x8*)(xws + (size_t)s1 * DD + c);
        bf16x8 v2 = *(const bf16x8*)(xws + (size_t)s2 * DD + c);
        bf16x8 v3 = *(const bf16x8*)(xws + (size_t)s3 * DD + c);
#pragma unroll
        for (int i = 0; i < 8; ++i)
            a[i] += d0 * (float)v0[i] + d1 * (float)v1[i] + d2 * (float)v2[i] + d3 * (float)v3[i];
    }
    for (; k < ne; ++k) {
        int s = csr[beg + k];
        float ds_ = dinv[s];
        bf16x8 v = *(const bf16x8*)(xws + (size_t)s * DD + c);
#pragma unroll
        for (int i = 0; i < 8; ++i) a[i] += ds_ * (float)v[i];
    }

    float al = alpha2[0];
    float g[8];
    float ss = 0.0f;
#pragma unroll
    for (int i = 0; i < 8; ++i) {
        float x = a[i] * dn + bg[c + i];
        x = (x >= 0.0f) ? x : al * x;
        g[i] = x;
        ss += x * x;
    }
#pragma unroll
    for (int off = 1; off < 64; off <<= 1) ss += __shfl_xor(ss, off, 64);
    float inv = 1.0f / fmaxf(sqrtf(ss), 1e-12f);

    size_t base = (size_t)node * DD + c;
    float4 t0 = *(const float4*)&text[base];
    float4 t1 = *(const float4*)&text[base + 4];
    float4 o0, o1;
    o0.x = g[0] * inv + t0.x; o0.y = g[1] * inv + t0.y;
    o0.z = g[2] * inv + t0.z; o0.w = g[3] * inv + t0.w;
    o1.x = g[4] * inv + t1.x; o1.y = g[5] * inv + t1.y;
    o1.z = g[6] * inv + t1.z; o1.w = g[7] * inv + t1.w;
    *(float4*)&out[base]     = o0;
    *(float4*)&out[base + 4] = o1;
}

extern "C" void kernel_launch(void* const* d_in, const int* in_sizes, int n_in,
                              void* d_out, int out_size, void* d_ws, size_t ws_size,
                              hipStream_t stream) {
    const float* text   = (const float*)d_in[0];
    const int*   esrc   = (const int*)d_in[1];
    const int*   edst   = (const int*)d_in[2];
    const float* W1     = (const float*)d_in[3];
    const float* b1     = (const float*)d_in[4];
    const float* gamma  = (const float*)d_in[5];
    const float* beta   = (const float*)d_in[6];
    const float* rmean  = (const float*)d_in[7];
    const float* rvar   = (const float*)d_in[8];
    const float* alpha1 = (const float*)d_in[9];
    const float* Wg     = (const float*)d_in[10];
    const float* bg     = (const float*)d_in[11];
    const float* alpha2 = (const float*)d_in[12];
    float* out = (float*)d_out;

    // workspace layout (~66.5 MiB)
    char* p = (char*)d_ws;
    auto alloc = [&](size_t bytes) { char* r = p; p += (bytes + 255) & ~(size_t)255; return r; };
    int*    cnt     = (int*)alloc((size_t)NN * 4);
    int*    offs    = (int*)alloc((size_t)(NN + 1) * 4);
    int*    cursor  = (int*)alloc((size_t)NN * 4);
    float*  dinv    = (float*)alloc((size_t)NN * 4);
    int*    csr     = (int*)alloc((size_t)EE * 4);
    __bf16* W1t     = (__bf16*)alloc((size_t)DD * DD * 2);
    __bf16* Wgt     = (__bf16*)alloc((size_t)DD * DD * 2);
    __bf16* h_bf    = (__bf16*)alloc((size_t)NN * DD * 2);
    __bf16* xws     = (__bf16*)alloc((size_t)NN * DD * 2);

    // 1) CSR build + dinv
    k_zero<<<NN / 256, 256, 0, stream>>>(cnt);
    k_count<<<EE / 256, 256, 0, stream>>>(edst, cnt);
    k_scan<<<1, 1024, 0, stream>>>(cnt, offs, cursor, dinv);
    k_fill<<<EE / 256, 256, 0, stream>>>(esrc, edst, cursor, csr);

    // 2) weights -> bf16 [n][k]
    k_wt<<<dim3(16, 16, 2), dim3(32, 8), 0, stream>>>(W1, Wg, W1t, Wgt);

    // 3) h = PReLU(BN(text@W1 + b1))   [LDS slab, r13 structure]
    k_gemm1<<<256, 512, 0, stream>>>(text, W1t, h_bf, b1, gamma, beta, rmean, rvar, alpha1);

    // 4) xws = h@Wg                    [barrier-free, A direct to VGPR]
    k_gemm2_bf<<<256, 512, 0, stream>>>(h_bf, Wgt, xws);

    // 5) fused gather (deg-weighted) + epilogue + L2 norm + residual
    k_gather_final<<<NN / 4, 256, 0, stream>>>(offs, csr, xws, dinv, bg, alpha2, text, out);
}

// Round 18
// 172.736 us; speedup vs baseline: 1.0714x; 1.0714x over previous
//
#include <hip/hip_runtime.h>
#include <math.h>

#define DD    512
#define NN    32768      // B*L nodes
#define EE    262144     // edges (without self loops)

typedef float f32x4 __attribute__((ext_vector_type(4)));
typedef __bf16 bf16x8 __attribute__((ext_vector_type(8)));

#define AS1 __attribute__((address_space(1)))
#define AS3 __attribute__((address_space(3)))

// ---------------- CSR build ----------------
__global__ void k_zero(int* __restrict__ cnt) {
    int i = blockIdx.x * 256 + threadIdx.x;
    if (i < NN) cnt[i] = 0;
}

__global__ void k_count(const int* __restrict__ dst, int* __restrict__ cnt) {
    int e = blockIdx.x * 256 + threadIdx.x;
    if (e < EE) atomicAdd(&cnt[dst[e]], 1);
}

__global__ __launch_bounds__(1024) void k_scan(
    const int* __restrict__ cnt, int* __restrict__ offs,
    int* __restrict__ cursor, float* __restrict__ dinv)
{
    __shared__ int part[1024];
    int t = threadIdx.x;
    int base = t * 32;
    int local[32];
    int s = 0;
#pragma unroll
    for (int i = 0; i < 32; ++i) { local[i] = s; s += cnt[base + i]; }
    part[t] = s;
    __syncthreads();
    for (int off = 1; off < 1024; off <<= 1) {
        int v = (t >= off) ? part[t - off] : 0;
        __syncthreads();
        part[t] += v;
        __syncthreads();
    }
    int prev = (t == 0) ? 0 : part[t - 1];
#pragma unroll
    for (int i = 0; i < 32; ++i) {
        int o = prev + local[i];
        offs[base + i] = o;
        cursor[base + i] = o;
        dinv[base + i] = rsqrtf((float)cnt[base + i] + 1.0f);
    }
    if (t == 1023) offs[NN] = part[1023];
}

__global__ void k_fill(const int* __restrict__ src, const int* __restrict__ dst,
                       int* __restrict__ cursor, int* __restrict__ csr) {
    int e = blockIdx.x * 256 + threadIdx.x;
    if (e < EE) {
        int d = dst[e];
        int p = atomicAdd(&cursor[d], 1);
        csr[p] = src[e];
    }
}

// ---------------- weight transpose + convert: Wt[n][k] = (bf16)W[k][n] ----------------
__global__ __launch_bounds__(256) void k_wt(const float* __restrict__ W1, const float* __restrict__ Wg,
                                            __bf16* __restrict__ W1t, __bf16* __restrict__ Wgt) {
    __shared__ float tile[32][33];
    const float* W = blockIdx.z ? Wg : W1;
    __bf16* Wt = blockIdx.z ? Wgt : W1t;
    int x0 = blockIdx.x * 32;   // n block
    int y0 = blockIdx.y * 32;   // k block
    int tx = threadIdx.x;       // 0..31
    for (int j = threadIdx.y; j < 32; j += 8)
        tile[j][tx] = W[(size_t)(y0 + j) * DD + x0 + tx];
    __syncthreads();
    for (int j = threadIdx.y; j < 32; j += 8)
        Wt[(size_t)(x0 + j) * DD + y0 + tx] = (__bf16)tile[tx][j];
}

// ---------------- FUSED MLP + GCN-linear: xws = PReLU(BN(text@W1+b1)) @ Wg ----------------
// 128-row panel per block, 8 waves, grid 256 (XCD-affine swizzle). LDS 160KB:
//   hbuf [16kf][128r][4s][8] bf16 = 128KB  (h panel, conflict-free kf-subtiled)
//   slab [16kf][ 32r][4s][8] bf16 =  32KB  (text m-tile, single-buffered + fa-reg prefetch)
// Phase 1 (per 32-row m-tile x 4, per col-pass x 2): W1-slice (32 cols, full K) in regs
//   (reloaded per pass from L2-hot W1t), A from slab, h-frags written to hbuf (LDS).
// Phase 2: ZERO global staging. Per col-pass x 2: Wg-slice in regs, A-frags ds_read
//   from hbuf, 256 MFMA/wave/pass, epilogue stores xws (unscaled; dinv in gather).
__global__ __launch_bounds__(512, 2) void k_fused(
    const float* __restrict__ A,       // text fp32
    const __bf16* __restrict__ W1t,
    const __bf16* __restrict__ Wgt,
    __bf16* __restrict__ Xout,         // xws
    const float* __restrict__ b1,
    const float* __restrict__ gamma, const float* __restrict__ beta,
    const float* __restrict__ mean, const float* __restrict__ var,
    const float* __restrict__ alphap)
{
    __shared__ __bf16 hbuf[65536];   // 128KB
    __shared__ __bf16 slab[16384];   // 32KB

    const int t    = threadIdx.x;
    const int lane = t & 63;
    const int wv   = t >> 6;
    const int l15  = lane & 15;
    const int lhi  = lane >> 4;
    const int work = ((blockIdx.x & 7) << 5) + (blockIdx.x >> 3);  // bijective 256; XCD-affine
    const int mbase = work * 128;

    // ---- BN/PReLU constants for both passes (phase-1 cols) ----
    float sc[2][2], tc[2][2];
    const float al = alphap[0];
#pragma unroll
    for (int p = 0; p < 2; ++p)
#pragma unroll
        for (int C = 0; C < 2; ++C) {
            int c = p * 256 + wv * 32 + C * 16 + l15;
            float r = rsqrtf(var[c] + 1e-5f);
            sc[p][C] = gamma[c] * r;
            tc[p][C] = (b1[c] - mean[c]) * sc[p][C] + beta[c];
        }

    float4 fa[4][2];   // text staging regs (one 32-row m-tile = 2048 chunks / 512 thr)

    auto loadA1 = [&](int mt) {
#pragma unroll
        for (int q = 0; q < 4; ++q) {
            int d = q * 512 + t;
            int kf = d >> 7, r = (d >> 2) & 31, s = d & 3;
            int c = kf * 4 + (s ^ ((r >> 1) & 3));
            const float* g = A + (size_t)(mbase + mt * 32 + r) * DD + c * 8;
            fa[q][0] = *(const float4*)g;
            fa[q][1] = *(const float4*)(g + 4);
        }
    };
    auto writeA1 = [&]() {
#pragma unroll
        for (int q = 0; q < 4; ++q) {
            int d = q * 512 + t;
            bf16x8 o;
            o[0] = (__bf16)fa[q][0].x; o[1] = (__bf16)fa[q][0].y;
            o[2] = (__bf16)fa[q][0].z; o[3] = (__bf16)fa[q][0].w;
            o[4] = (__bf16)fa[q][1].x; o[5] = (__bf16)fa[q][1].y;
            o[6] = (__bf16)fa[q][1].z; o[7] = (__bf16)fa[q][1].w;
            *(bf16x8*)&slab[(size_t)d * 8] = o;
        }
    };

    // ---- phase 1 prologue ----
    loadA1(0); writeA1();
    __syncthreads();

    // ---- phase 1: 4 m-tiles x 2 col-passes ----
#pragma unroll
    for (int mt = 0; mt < 4; ++mt) {
        if (mt < 3) loadA1(mt + 1);   // fa regs; flies under ~10k cyc of compute

#pragma unroll
        for (int pass = 0; pass < 2; ++pass) {
            // W1 slice for this pass (32 cols x full K) — L2-hot, reload cheap
            bf16x8 wf[2][16];
#pragma unroll
            for (int C = 0; C < 2; ++C)
#pragma unroll
                for (int kf = 0; kf < 16; ++kf) {
                    int col = pass * 256 + wv * 32 + C * 16 + l15;
                    wf[C][kf] = *(const bf16x8*)(W1t + (size_t)col * DD + kf * 32 + lhi * 8);
                }

            f32x4 acc[2][2] = {};
#pragma unroll
            for (int kf = 0; kf < 16; ++kf) {
                int r0 = l15, r1 = 16 + l15;
                int sA = lhi ^ ((r0 >> 1) & 3);
                int sB = lhi ^ ((r1 >> 1) & 3);
                bf16x8 a0 = *(const bf16x8*)&slab[(kf * 128 + r0 * 4 + sA) * 8];
                bf16x8 a1 = *(const bf16x8*)&slab[(kf * 128 + r1 * 4 + sB) * 8];
                acc[0][0] = __builtin_amdgcn_mfma_f32_16x16x32_bf16(a0, wf[0][kf], acc[0][0], 0, 0, 0);
                acc[0][1] = __builtin_amdgcn_mfma_f32_16x16x32_bf16(a0, wf[1][kf], acc[0][1], 0, 0, 0);
                acc[1][0] = __builtin_amdgcn_mfma_f32_16x16x32_bf16(a1, wf[0][kf], acc[1][0], 0, 0, 0);
                acc[1][1] = __builtin_amdgcn_mfma_f32_16x16x32_bf16(a1, wf[1][kf], acc[1][1], 0, 0, 0);
            }

            // h-frags -> hbuf (k dim = phase-1 col)
#pragma unroll
            for (int R = 0; R < 2; ++R)
#pragma unroll
                for (int C = 0; C < 2; ++C) {
                    int k = pass * 256 + wv * 32 + C * 16 + l15;
                    int kf2 = k >> 5, kc = (k >> 3) & 3, kb = k & 7;
#pragma unroll
                    for (int j = 0; j < 4; ++j) {
                        int row = mt * 32 + R * 16 + (lhi << 2) + j;
                        float x = acc[R][C][j] * sc[pass][C] + tc[pass][C];
                        x = (x >= 0.0f) ? x : al * x;
                        int s2 = kc ^ ((row >> 1) & 3);
                        hbuf[(size_t)(kf2 * 512 + row * 4 + s2) * 8 + kb] = (__bf16)x;
                    }
                }
        }

        __syncthreads();                 // all waves done reading slab (and h-writes drained)
        if (mt < 3) {
            writeA1();                   // next m-tile into slab
            __syncthreads();             // slab ready
        }
    }
    // after mt=3's __syncthreads: hbuf fully written & visible

    // ---- phase 2: xws = h @ Wg, A purely from LDS ----
#pragma unroll
    for (int pass = 0; pass < 2; ++pass) {
        bf16x8 wg[2][16];
#pragma unroll
        for (int C = 0; C < 2; ++C)
#pragma unroll
            for (int kf = 0; kf < 16; ++kf) {
                int col = pass * 256 + wv * 32 + C * 16 + l15;
                wg[C][kf] = *(const bf16x8*)(Wgt + (size_t)col * DD + kf * 32 + lhi * 8);
            }

        f32x4 acc2[8][2] = {};
#pragma unroll
        for (int kf = 0; kf < 16; ++kf) {
            bf16x8 af[8];
#pragma unroll
            for (int rg = 0; rg < 8; ++rg) {
                int r = rg * 16 + l15;
                int s = lhi ^ ((r >> 1) & 3);
                af[rg] = *(const bf16x8*)&hbuf[(size_t)(kf * 512 + r * 4 + s) * 8];
            }
#pragma unroll
            for (int rg = 0; rg < 8; ++rg) {
                acc2[rg][0] = __builtin_amdgcn_mfma_f32_16x16x32_bf16(af[rg], wg[0][kf], acc2[rg][0], 0, 0, 0);
                acc2[rg][1] = __builtin_amdgcn_mfma_f32_16x16x32_bf16(af[rg], wg[1][kf], acc2[rg][1], 0, 0, 0);
            }
        }

#pragma unroll
        for (int rg = 0; rg < 8; ++rg)
#pragma unroll
            for (int C = 0; C < 2; ++C) {
                int col  = pass * 256 + wv * 32 + C * 16 + l15;
                int rowb = mbase + rg * 16 + (lhi << 2);
#pragma unroll
                for (int j = 0; j < 4; ++j)
                    Xout[(size_t)(rowb + j) * DD + col] = (__bf16)acc2[rg][C][j];
            }
    }
}

// ---------------- fused gather (deg-weighted) + bias + PReLU + L2 norm + residual ----------------
__global__ __launch_bounds__(256) void k_gather_final(
    const int* __restrict__ offs, const int* __restrict__ csr,
    const __bf16* __restrict__ xws, const float* __restrict__ dinv,
    const float* __restrict__ bg, const float* __restrict__ alpha2,
    const float* __restrict__ text, float* __restrict__ out)
{
    int blk = blockIdx.x;                              // 0..8191
    int sb  = ((blk & 7) << 10) + (blk >> 3);          // XCD-chunked (bijective)
    int wave = threadIdx.x >> 6;
    int lane = threadIdx.x & 63;
    int node = sb * 4 + wave;
    int c = lane * 8;
    int beg = offs[node], end = offs[node + 1];
    int ne = end - beg;

    float dn = dinv[node];
    bf16x8 sv = *(const bf16x8*)(xws + (size_t)node * DD + c);   // self loop
    float a[8];
#pragma unroll
    for (int i = 0; i < 8; ++i) a[i] = dn * (float)sv[i];

    int k = 0;
    for (; k + 4 <= ne; k += 4) {
        int s0 = csr[beg + k + 0];
        int s1 = csr[beg + k + 1];
        int s2 = csr[beg + k + 2];
        int s3 = csr[beg + k + 3];
        float d0 = dinv[s0], d1 = dinv[s1], d2 = dinv[s2], d3 = dinv[s3];
        bf16x8 v0 = *(const bf16x8*)(xws + (size_t)s0 * DD + c);
        bf16x8 v1 = *(const bf16x8*)(xws + (size_t)s1 * DD + c);
        bf16x8 v2 = *(const bf16x8*)(xws + (size_t)s2 * DD + c);
        bf16x8 v3 = *(const bf16x8*)(xws + (size_t)s3 * DD + c);
#pragma unroll
        for (int i = 0; i < 8; ++i)
            a[i] += d0 * (float)v0[i] + d1 * (float)v1[i] + d2 * (float)v2[i] + d3 * (float)v3[i];
    }
    for (; k < ne; ++k) {
        int s = csr[beg + k];
        float ds_ = dinv[s];
        bf16x8 v = *(const bf16x8*)(xws + (size_t)s * DD + c);
#pragma unroll
        for (int i = 0; i < 8; ++i) a[i] += ds_ * (float)v[i];
    }

    float al = alpha2[0];
    float g[8];
    float ss = 0.0f;
#pragma unroll
    for (int i = 0; i < 8; ++i) {
        float x = a[i] * dn + bg[c + i];
        x = (x >= 0.0f) ? x : al * x;
        g[i] = x;
        ss += x * x;
    }
#pragma unroll
    for (int off = 1; off < 64; off <<= 1) ss += __shfl_xor(ss, off, 64);
    float inv = 1.0f / fmaxf(sqrtf(ss), 1e-12f);

    size_t base = (size_t)node * DD + c;
    float4 t0 = *(const float4*)&text[base];
    float4 t1 = *(const float4*)&text[base + 4];
    float4 o0, o1;
    o0.x = g[0] * inv + t0.x; o0.y = g[1] * inv + t0.y;
    o0.z = g[2] * inv + t0.z; o0.w = g[3] * inv + t0.w;
    o1.x = g[4] * inv + t1.x; o1.y = g[5] * inv + t1.y;
    o1.z = g[6] * inv + t1.z; o1.w = g[7] * inv + t1.w;
    *(float4*)&out[base]     = o0;
    *(float4*)&out[base + 4] = o1;
}

extern "C" void kernel_launch(void* const* d_in, const int* in_sizes, int n_in,
                              void* d_out, int out_size, void* d_ws, size_t ws_size,
                              hipStream_t stream) {
    const float* text   = (const float*)d_in[0];
    const int*   esrc   = (const int*)d_in[1];
    const int*   edst   = (const int*)d_in[2];
    const float* W1     = (const float*)d_in[3];
    const float* b1     = (const float*)d_in[4];
    const float* gamma  = (const float*)d_in[5];
    const float* beta   = (const float*)d_in[6];
    const float* rmean  = (const float*)d_in[7];
    const float* rvar   = (const float*)d_in[8];
    const float* alpha1 = (const float*)d_in[9];
    const float* Wg     = (const float*)d_in[10];
    const float* bg     = (const float*)d_in[11];
    const float* alpha2 = (const float*)d_in[12];
    float* out = (float*)d_out;

    // workspace layout (~36 MiB)
    char* p = (char*)d_ws;
    auto alloc = [&](size_t bytes) { char* r = p; p += (bytes + 255) & ~(size_t)255; return r; };
    int*    cnt     = (int*)alloc((size_t)NN * 4);
    int*    offs    = (int*)alloc((size_t)(NN + 1) * 4);
    int*    cursor  = (int*)alloc((size_t)NN * 4);
    float*  dinv    = (float*)alloc((size_t)NN * 4);
    int*    csr     = (int*)alloc((size_t)EE * 4);
    __bf16* W1t     = (__bf16*)alloc((size_t)DD * DD * 2);
    __bf16* Wgt     = (__bf16*)alloc((size_t)DD * DD * 2);
    __bf16* xws     = (__bf16*)alloc((size_t)NN * DD * 2);

    // 1) CSR build + dinv
    k_zero<<<NN / 256, 256, 0, stream>>>(cnt);
    k_count<<<EE / 256, 256, 0, stream>>>(edst, cnt);
    k_scan<<<1, 1024, 0, stream>>>(cnt, offs, cursor, dinv);
    k_fill<<<EE / 256, 256, 0, stream>>>(esrc, edst, cursor, csr);

    // 2) weights -> bf16 [n][k]
    k_wt<<<dim3(16, 16, 2), dim3(32, 8), 0, stream>>>(W1, Wg, W1t, Wgt);

    // 3) fused: xws = PReLU(BN(text@W1+b1)) @ Wg   (h stays in LDS)
    k_fused<<<256, 512, 0, stream>>>(text, W1t, Wgt, xws, b1, gamma, beta, rmean, rvar, alpha1);

    // 4) fused gather (deg-weighted) + epilogue + L2 norm + residual
    k_gather_final<<<NN / 4, 256, 0, stream>>>(offs, csr, xws, dinv, bg, alpha2, text, out);
}